// Round 1
// 335.825 us; speedup vs baseline: 1.0911x; 1.0911x over previous
//
#include <hip/hip_runtime.h>
#include <hip/hip_bf16.h>

#define NQ 65536
#define DIM 512
#define HID 256
#define NWAY 5
#define NKPTS 17

typedef short bf16x8 __attribute__((ext_vector_type(8)));
typedef float f32x4 __attribute__((ext_vector_type(4)));
typedef _Float16 half8 __attribute__((ext_vector_type(8)));

static __device__ __forceinline__ unsigned short f2bf(float f) {
    unsigned int x = __float_as_uint(f);
    unsigned int r = (x + 0x7fffu + ((x >> 16) & 1u)) >> 16;
    return (unsigned short)r;
}

static __device__ __forceinline__ void async16(void* l, const void* g) {
    __builtin_amdgcn_global_load_lds(
        (const __attribute__((address_space(1))) unsigned int*)g,
        (__attribute__((address_space(3))) unsigned int*)l, 16, 0, 0);
}

// ---------------- support layer 1: ws_h1 = relu(sf@W1+b1), coalesced over columns ----------
// grid 200: s = bx>>3 (0..24), cb = bx&7 (64-col strip). W1 loads: 64 consecutive floats/wave.
__global__ __launch_bounds__(256) void k_sup(const float* __restrict__ sf,
                                             const float* __restrict__ W1, const float* __restrict__ b1,
                                             float* __restrict__ ws_h1) {
    __shared__ float sfl[512];
    __shared__ float red[4][64];
    int bx = blockIdx.x;
    int s = bx >> 3, cb = bx & 7;
    int t = threadIdx.x;
    if (t < 128) ((float4*)sfl)[t] = ((const float4*)(sf + s * DIM))[t];
    __syncthreads();
    int c = cb * 64 + (t & 63);
    int qd = t >> 6;                 // k-quarter 0..3 (wave-uniform)
    const float* Wp = W1 + (size_t)qd * 128 * DIM + c;
    float acc = 0.0f;
    #pragma unroll 4
    for (int kk = 0; kk < 128; kk++)
        acc += sfl[qd * 128 + kk] * Wp[(size_t)kk * DIM];
    red[qd][t & 63] = acc;
    __syncthreads();
    if (t < 64) {
        float h = red[0][t] + red[1][t] + red[2][t] + red[3][t] + b1[cb * 64 + t];
        ws_h1[s * DIM + cb * 64 + t] = fmaxf(h, 0.0f);
    }
}

// ---------------- k_mid2: prototypes (mean then W2, coalesced) + [Wo1|Wc1] transpose->bf16 ----
__global__ __launch_bounds__(256) void k_mid2(const float* __restrict__ ws_h1,
                                              const float* __restrict__ W2, const float* __restrict__ b2,
                                              const float* __restrict__ Wo1, const float* __restrict__ Wc1,
                                              float* __restrict__ ws_proto, unsigned short* __restrict__ wb) {
    int bx = blockIdx.x;
    int t = threadIdx.x;
    if (bx < 40) {
        __shared__ float ml[512];
        __shared__ float red[4][64];
        int w = bx >> 3, cb = bx & 7;
        for (int i = t; i < 512; i += 256) {
            float sum = 0.0f;
            #pragma unroll
            for (int s5 = 0; s5 < 5; s5++) sum += ws_h1[(w * 5 + s5) * DIM + i];
            ml[i] = sum * 0.2f;
        }
        __syncthreads();
        int c = cb * 64 + (t & 63);
        int qd = t >> 6;
        const float* Wp = W2 + (size_t)qd * 128 * DIM + c;
        float acc = 0.0f;
        #pragma unroll 4
        for (int kk = 0; kk < 128; kk++)
            acc += ml[qd * 128 + kk] * Wp[(size_t)kk * DIM];
        red[qd][t & 63] = acc;
        __syncthreads();
        if (t < 64)
            ws_proto[w * DIM + cb * 64 + t] =
                red[0][t] + red[1][t] + red[2][t] + red[3][t] + b2[cb * 64 + t];
    } else {
        __shared__ unsigned short T[64][72];
        int tb = bx - 40;                    // 0..63
        const float* src = (tb < 32) ? Wo1 : Wc1;
        int cofs = (tb < 32) ? 0 : 256;
        int tt = tb & 31;
        int kt = tt >> 2;                    // k-tile 0..7
        int ct = tt & 3;                     // c-tile 0..3
        int i = t >> 2;                      // k row within tile 0..63
        int qd = t & 3;
        const float* rp = src + (size_t)(kt * 64 + i) * HID + ct * 64 + qd * 16;
        #pragma unroll
        for (int v = 0; v < 4; v++) {
            float4 x = *(const float4*)(rp + v * 4);
            T[qd * 16 + v * 4 + 0][i] = f2bf(x.x);
            T[qd * 16 + v * 4 + 1][i] = f2bf(x.y);
            T[qd * 16 + v * 4 + 2][i] = f2bf(x.z);
            T[qd * 16 + v * 4 + 3][i] = f2bf(x.w);
        }
        __syncthreads();
        int j = t >> 2;                      // c within tile
        int part = t & 3;
        uint4 o0 = *(const uint4*)&T[j][part * 16];
        uint4 o1 = *(const uint4*)&T[j][part * 16 + 8];
        unsigned short* dst = wb + (size_t)(cofs + ct * 64 + j) * DIM + kt * 64 + part * 16;
        *(uint4*)dst = o0;
        *(uint4*)(dst + 8) = o1;
    }
}

// ---------------- prepass: qf -> bf16 + f32 distances/argmin + dist/class/proto outputs -----
// grid 2048 x 256. Wave handles 8 queries; protos held per-lane (8-elem slices) in registers.
__global__ __launch_bounds__(256) void k_prep(const float* __restrict__ qf,
                                              const float* __restrict__ ws_proto,
                                              const float* __restrict__ temp_p,
                                              unsigned short* __restrict__ qbf,
                                              float* __restrict__ out_dist, float* __restrict__ out_class,
                                              float* __restrict__ out_proto) {
    __shared__ float dlds[32 * NWAY];
    int bx = blockIdx.x, t = threadIdx.x;
    int wv = t >> 6, lane = t & 63;

    // out_proto broadcast (spread over blocks 0..84)
    if (bx < NWAY * NKPTS && t < 128) {
        f32x4 v = *(const f32x4*)(ws_proto + (bx / NKPTS) * DIM + t * 4);
        *(f32x4*)(out_proto + (size_t)bx * DIM + t * 4) = v;
    }

    float p[NWAY][8];
    float pn[NWAY];
    {
        float pp[NWAY];
        #pragma unroll
        for (int w = 0; w < NWAY; w++) {
            f32x4 a = *(const f32x4*)(ws_proto + w * DIM + lane * 8);
            f32x4 b = *(const f32x4*)(ws_proto + w * DIM + lane * 8 + 4);
            p[w][0] = a[0]; p[w][1] = a[1]; p[w][2] = a[2]; p[w][3] = a[3];
            p[w][4] = b[0]; p[w][5] = b[1]; p[w][6] = b[2]; p[w][7] = b[3];
            float s = 0.0f;
            #pragma unroll
            for (int j = 0; j < 8; j++) s += p[w][j] * p[w][j];
            pp[w] = s;
        }
        #pragma unroll
        for (int off = 32; off > 0; off >>= 1) {
            #pragma unroll
            for (int w = 0; w < NWAY; w++) pp[w] += __shfl_xor(pp[w], off, 64);
        }
        #pragma unroll
        for (int w = 0; w < NWAY; w++) pn[w] = sqrtf(pp[w]);
    }
    float invt = 1.0f / temp_p[0];

    int qbase = bx * 32 + wv * 8;
    for (int qi = 0; qi < 8; qi++) {
        int Q = qbase + qi;
        const float* vp = qf + (size_t)Q * DIM + lane * 8;
        float4 v0 = *(const float4*)vp;
        float4 v1 = *(const float4*)(vp + 4);
        unsigned int r0 = f2bf(v0.x) | ((unsigned int)f2bf(v0.y) << 16);
        unsigned int r1 = f2bf(v0.z) | ((unsigned int)f2bf(v0.w) << 16);
        unsigned int r2 = f2bf(v1.x) | ((unsigned int)f2bf(v1.y) << 16);
        unsigned int r3 = f2bf(v1.z) | ((unsigned int)f2bf(v1.w) << 16);
        *(uint4*)(qbf + (size_t)Q * DIM + lane * 8) = make_uint4(r0, r1, r2, r3);

        float av[8] = {v0.x, v0.y, v0.z, v0.w, v1.x, v1.y, v1.z, v1.w};
        float d[NWAY + 1];
        #pragma unroll
        for (int w = 0; w < NWAY; w++) {
            float s = 0.0f;
            #pragma unroll
            for (int j = 0; j < 8; j++) s += av[j] * p[w][j];
            d[w] = s;
        }
        {
            float s = 0.0f;
            #pragma unroll
            for (int j = 0; j < 8; j++) s += av[j] * av[j];
            d[NWAY] = s;
        }
        #pragma unroll
        for (int off = 32; off > 0; off >>= 1) {
            #pragma unroll
            for (int k2 = 0; k2 < NWAY + 1; k2++) d[k2] += __shfl_xor(d[k2], off, 64);
        }
        float qn = sqrtf(d[NWAY]);
        float mv = 1e30f; int ami = 0;
        float d0, d1c, d2c, d3c, d4c;
        {
            float dist[NWAY];
            #pragma unroll
            for (int w = 0; w < NWAY; w++) {
                float den = fmaxf(qn * pn[w], 1e-8f);
                float dd = (1.0f - d[w] / den) * invt;
                dist[w] = dd;
                if (dd < mv) { mv = dd; ami = w; }
            }
            d0 = dist[0]; d1c = dist[1]; d2c = dist[2]; d3c = dist[3]; d4c = dist[4];
        }
        if (lane == 0) {
            out_class[Q] = (float)ami;
            int b0 = (wv * 8 + qi) * NWAY;
            dlds[b0 + 0] = d0; dlds[b0 + 1] = d1c; dlds[b0 + 2] = d2c;
            dlds[b0 + 3] = d3c; dlds[b0 + 4] = d4c;
        }
    }
    __syncthreads();
    int Q0 = bx * 32;
    for (int i = t; i < 32 * NWAY * NKPTS; i += 256) {
        int q2 = i / (NWAY * NKPTS);
        int rem = i - q2 * (NWAY * NKPTS);
        out_dist[(size_t)(Q0 + q2) * (NWAY * NKPTS) + rem] = dlds[q2 * NWAY + rem / NKPTS];
    }
}

// ---------------- MFMA GEMM: [65536x512(bf16)] x [512x512(bf16)]^T-stored + fused heads -----
// tile 128x256, BK=64, 512 thr / 8 waves (2Mx4N, wave=64x64), global_load_lds + XOR swizzle,
// double-buffered, one barrier per K-step (T3 minimal 2-phase). grid = 512 mtiles x 2 heads.
__global__ __launch_bounds__(512) void k_gemm(const unsigned short* __restrict__ qbf,
                                              const unsigned short* __restrict__ wb,
                                              const float* __restrict__ bo1, const float* __restrict__ Wo2,
                                              const float* __restrict__ bo2,
                                              const float* __restrict__ bc1, const float* __restrict__ Wc2,
                                              const float* __restrict__ bc2,
                                              const float* __restrict__ ic,
                                              float* __restrict__ out_kp, float* __restrict__ out_conf) {
    __shared__ __align__(16) char smem[98304];
    unsigned short* Ab = (unsigned short*)smem;              // [2][128 rows][64 k] bf16, 2x16KB
    unsigned short* Bb = (unsigned short*)(smem + 32768);    // [2][256 cols][64 k] bf16, 2x32KB

    int bx = blockIdx.x;
    int mb = bx >> 1, nb = bx & 1;
    int t = threadIdx.x;
    int wv = t >> 6, lane = t & 63;
    int wr = wv >> 2, wc = wv & 3;
    int r = lane & 15, hq = lane >> 4;

    // staging lane addressing: 1KB chunk = 8 rows x 128B; slot pre-swizzled in the GLOBAL src
    int lrow = lane >> 3;                    // row within chunk (== row&7)
    int lslot = (lane & 7) ^ lrow;           // inverse-swizzled 16B slot
    const unsigned short* Ag = qbf + (size_t)mb * (128 * DIM) + (size_t)lrow * DIM + lslot * 8;
    const unsigned short* Bg = wb + (size_t)nb * (HID * DIM) + (size_t)lrow * DIM + lslot * 8;

    f32x4 acc[4][4];
    #pragma unroll
    for (int i2 = 0; i2 < 4; i2++)
        #pragma unroll
        for (int j2 = 0; j2 < 4; j2++) { f32x4 z = {0.0f, 0.0f, 0.0f, 0.0f}; acc[i2][j2] = z; }

    // prologue: stage tile 0 into parity 0
    #pragma unroll
    for (int i = 0; i < 2; i++) {
        int ci = wv * 2 + i;                 // A chunks 0..15
        async16(smem + ci * 1024, Ag + (size_t)ci * 8 * DIM);
    }
    #pragma unroll
    for (int i = 0; i < 4; i++) {
        int ci = wv * 4 + i;                 // B chunks 0..31
        async16(smem + 32768 + ci * 1024, Bg + (size_t)ci * 8 * DIM);
    }
    __syncthreads();

    for (int it = 0; it < 8; it++) {
        int par = it & 1;
        if (it < 7) {                        // stage next tile into other parity (in flight over MFMA)
            int ko = (it + 1) * 64;
            int pn2 = par ^ 1;
            #pragma unroll
            for (int i = 0; i < 2; i++) {
                int ci = wv * 2 + i;
                async16(smem + pn2 * 16384 + ci * 1024, Ag + (size_t)ci * 8 * DIM + ko);
            }
            #pragma unroll
            for (int i = 0; i < 4; i++) {
                int ci = wv * 4 + i;
                async16(smem + 32768 + pn2 * 32768 + ci * 1024, Bg + (size_t)ci * 8 * DIM + ko);
            }
        }
        const unsigned short* Ap = Ab + par * 8192;
        const unsigned short* Bp = Bb + par * 16384;
        #pragma unroll
        for (int ks = 0; ks < 2; ks++) {
            int slot = ks * 4 + hq;
            bf16x8 af[4], bfr[4];
            #pragma unroll
            for (int mt = 0; mt < 4; mt++) {
                int m = wr * 64 + mt * 16 + r;
                af[mt] = *(const bf16x8*)(Ap + m * 64 + ((slot ^ (m & 7)) * 8));
            }
            #pragma unroll
            for (int nt = 0; nt < 4; nt++) {
                int c = wc * 64 + nt * 16 + r;
                bfr[nt] = *(const bf16x8*)(Bp + c * 64 + ((slot ^ (c & 7)) * 8));
            }
            #pragma unroll
            for (int mt = 0; mt < 4; mt++)
                #pragma unroll
                for (int nt = 0; nt < 4; nt++)
                    acc[mt][nt] = __builtin_amdgcn_mfma_f32_16x16x32_bf16(af[mt], bfr[nt], acc[mt][nt], 0, 0, 0);
        }
        __syncthreads();
    }

    // ---- epilogue: bias+relu -> f16 LDS [128][264], then per-query head dot, all 512 thr ----
    const float* bias = nb ? bc1 : bo1;
    _Float16* hl = (_Float16*)smem;
    #pragma unroll
    for (int nt = 0; nt < 4; nt++) {
        int cl = wc * 64 + nt * 16 + r;
        float bv = bias[cl];
        #pragma unroll
        for (int mt = 0; mt < 4; mt++)
            #pragma unroll
            for (int rg = 0; rg < 4; rg++) {
                int ml = wr * 64 + mt * 16 + hq * 4 + rg;
                hl[ml * 264 + cl] = (_Float16)fmaxf(acc[mt][nt][rg] + bv, 0.0f);
            }
    }
    __syncthreads();

    float* redf = (float*)(smem + 128 * 264 * 2);   // 67584: partial sums [4][128][..]
    int q = t & 127, qt = t >> 7;                   // qt wave-uniform
    if (nb == 0) {
        float ox = 0.0f, oy = 0.0f;
        #pragma unroll 2
        for (int j0 = 0; j0 < 64; j0 += 8) {
            half8 hv = *(const half8*)(hl + q * 264 + qt * 64 + j0);
            #pragma unroll
            for (int j = 0; j < 8; j++) {
                float2 w2 = *(const float2*)(Wo2 + (qt * 64 + j0 + j) * 2);
                float hf = (float)hv[j];
                ox += hf * w2.x;
                oy += hf * w2.y;
            }
        }
        redf[(qt * 128 + q) * 2] = ox;
        redf[(qt * 128 + q) * 2 + 1] = oy;
        __syncthreads();
        if (t < 128) {
            float sx = bo2[0], sy = bo2[1];
            #pragma unroll
            for (int k2 = 0; k2 < 4; k2++) {
                sx += redf[(k2 * 128 + t) * 2];
                sy += redf[(k2 * 128 + t) * 2 + 1];
            }
            size_t Q = (size_t)mb * 128 + t;
            float2 icv = *(const float2*)(ic + Q * 2);
            float gx = icv.x / (1.0f + __expf(-sx));
            float gy = icv.y / (1.0f + __expf(-sy));
            float2 g2 = make_float2(gx, gy);
            float2* dst = (float2*)(out_kp + Q * 34);
            #pragma unroll
            for (int k2 = 0; k2 < 17; k2++) dst[k2] = g2;
        }
    } else {
        float cs = 0.0f;
        #pragma unroll 2
        for (int j0 = 0; j0 < 64; j0 += 8) {
            half8 hv = *(const half8*)(hl + q * 264 + qt * 64 + j0);
            #pragma unroll
            for (int j = 0; j < 8; j++)
                cs += (float)hv[j] * Wc2[qt * 64 + j0 + j];
        }
        redf[qt * 128 + q] = cs;
        __syncthreads();
        if (t < 128) {
            float s = bc2[0] + redf[t] + redf[128 + t] + redf[256 + t] + redf[384 + t];
            float sg = 1.0f / (1.0f + __expf(-s));
            size_t Q = (size_t)mb * 128 + t;
            float* dst = out_conf + Q * 17;
            #pragma unroll
            for (int k2 = 0; k2 < 17; k2++) dst[k2] = sg;
        }
    }
}

extern "C" void kernel_launch(void* const* d_in, const int* in_sizes, int n_in,
                              void* d_out, int out_size, void* d_ws, size_t ws_size,
                              hipStream_t stream) {
    const float* sf = (const float*)d_in[0];
    const float* qf = (const float*)d_in[2];
    const float* ic = (const float*)d_in[3];
    const float* W1 = (const float*)d_in[4];
    const float* b1 = (const float*)d_in[5];
    const float* W2 = (const float*)d_in[6];
    const float* b2 = (const float*)d_in[7];
    const float* Wo1 = (const float*)d_in[8];
    const float* bo1 = (const float*)d_in[9];
    const float* Wo2 = (const float*)d_in[10];
    const float* bo2 = (const float*)d_in[11];
    const float* Wc1 = (const float*)d_in[12];
    const float* bc1 = (const float*)d_in[13];
    const float* Wc2 = (const float*)d_in[14];
    const float* bc2 = (const float*)d_in[15];
    const float* temp = (const float*)d_in[16];

    float* out = (float*)d_out;
    float* out_kp = out;                   // 65536*17*2
    float* out_conf = out + 2228224;       // 65536*17
    float* out_dist = out + 3342336;       // 65536*5*17
    float* out_class = out + 8912896;      // 65536
    float* out_proto = out + 8978432;      // 5*17*512

    char* ws = (char*)d_ws;
    float* ws_h1 = (float*)ws;                               // 25*512 f32
    float* ws_proto = (float*)(ws + 51200);                  // 5*512 f32
    unsigned short* ws_wb = (unsigned short*)(ws + 65536);   // 512*512 bf16 (transposed [Wo1|Wc1])
    unsigned short* ws_qbf = (unsigned short*)(ws + 1048576);// 65536*512 bf16 query features

    hipLaunchKernelGGL(k_sup, dim3(200), dim3(256), 0, stream, sf, W1, b1, ws_h1);
    hipLaunchKernelGGL(k_mid2, dim3(104), dim3(256), 0, stream, ws_h1, W2, b2, Wo1, Wc1, ws_proto, ws_wb);
    hipLaunchKernelGGL(k_prep, dim3(2048), dim3(256), 0, stream, qf, ws_proto, temp,
                       ws_qbf, out_dist, out_class, out_proto);
    hipLaunchKernelGGL(k_gemm, dim3(1024), dim3(512), 0, stream, ws_qbf, ws_wb,
                       bo1, Wo2, bo2, bc1, Wc2, bc2, ic, out_kp, out_conf);
}